// Round 21
// baseline (194.113 us; speedup 1.0000x reference)
//
#include <hip/hip_runtime.h>
#include <math.h>

#define B 64
#define T 4096
#define H 256
#define D 128
#define O 128
#define EPS 1e-5f

#define NCHUNK 64    // T/64 score chunks (= k2 grid.x)

typedef _Float16 half8 __attribute__((ext_vector_type(8)));
typedef float f32x4 __attribute__((ext_vector_type(4)));

__device__ __forceinline__ float rcp_fast(float x) {
  float r;
  asm("v_rcp_f32 %0, %1" : "=v"(r) : "v"(x));
  return r;
}

// lean tanh: 1 - 2*rcp(exp(2x)+1); exp overflow -> 1, underflow -> -1
__device__ __forceinline__ float tanh_fast(float x) {
  return fmaf(-2.f, rcp_fast(__expf(2.f * x) + 1.f), 1.f);
}

// ---------------- K0: permute W_e into f16 MFMA-fragment order ----
__global__ __launch_bounds__(256) void k0_permW(const float* __restrict__ attn_W,
                                               _Float16* __restrict__ Bperm) {
  int idx = blockIdx.x * 256 + threadIdx.x;
  int j = idx & 7;
  int l = (idx >> 3) & 63;
  int kt = (idx >> 9) & 7;
  int nt = idx >> 12;
  int g = nt * 16 + (l & 15);
  int k = kt * 32 + ((l >> 4) << 3) + j;
  Bperm[idx] = (_Float16)attn_W[(size_t)g * (2 * H) + H + k];
}

// ---------------- K1 ----
__global__ __launch_bounds__(256) void k1_hidproj_gh(
    const float* __restrict__ last_hidden, const float* __restrict__ attn_W,
    const float* __restrict__ attn_b, const float* __restrict__ W_hh,
    const float* __restrict__ b_hh, float* __restrict__ hid_proj,
    float* __restrict__ gh) {
  int b = blockIdx.x;
  int g = threadIdx.x;
  __shared__ __align__(16) float hp[H];
  hp[g] = last_hidden[b * H + g];
  __syncthreads();
  const float4* hp4 = reinterpret_cast<const float4*>(hp);
  const float4* wr = reinterpret_cast<const float4*>(attn_W + (size_t)g * (2 * H));
  float acc = attn_b[g];
#pragma unroll 8
  for (int h4 = 0; h4 < H / 4; ++h4) {
    float4 w = wr[h4], x = hp4[h4];
    acc += w.x * x.x + w.y * x.y + w.z * x.z + w.w * x.w;
  }
  hid_proj[b * H + g] = acc;
#pragma unroll
  for (int k = 0; k < 3; ++k) {
    int row = k * H + g;
    const float4* whr = reinterpret_cast<const float4*>(W_hh + (size_t)row * H);
    float a2 = b_hh[row];
#pragma unroll 8
    for (int h4 = 0; h4 < H / 4; ++h4) {
      float4 w = whr[h4], x = hp4[h4];
      a2 += w.x * x.x + w.y * x.y + w.z * x.z + w.w * x.w;
    }
    gh[(size_t)b * (3 * H) + row] = a2;
  }
}

// ======== K2 fused: scores (MFMA) + chunk-softmax + partial context ========
// R11/R20-verified structure. (256,4): LDS 34KB -> 4 blocks/CU (16 waves);
// VGPR use ~68 < 128 cap, so no squeeze. Heterogeneous phases (mem stage /
// MFMA / VALU ctx) across 4 independent blocks can overlap.
__global__ __launch_bounds__(256, 4) void k2_fused(
    const float* __restrict__ enc, const _Float16* __restrict__ Bperm,
    const float* __restrict__ hid_proj, const float* __restrict__ v,
    float* __restrict__ scores, float* __restrict__ cp,
    float* __restrict__ mbuf, float* __restrict__ lbuf) {
  const int b = blockIdx.y;
  const int chunk = blockIdx.x;
  const int t0 = chunk * 64;
  const int tid = threadIdx.x;
  const int wave = tid >> 6;
  const int lane = tid & 63;
  const int r = lane & 15;
  const int grp = lane >> 4;

  __shared__ __align__(16) _Float16 Alds[4 * 8 * 64 * 8];  // 32KB
  __shared__ float spart[4][64];
  __shared__ float wbuf[64];

  // ---- stage enc tile -> f16 fragment order (conflict-free writes) ----
  {
    const int rbase = tid & 7;
    const int kg = tid >> 3;
    const int kt_s = kg >> 2;
    const int lhi = (kg & 3) << 4;
#pragma unroll
    for (int i = 0; i < 8; ++i) {
      int row = i * 8 + rbase;
      const float* src = enc + ((size_t)(t0 + row) * B + b) * H + kg * 8;
      float4 x0 = *reinterpret_cast<const float4*>(src);
      float4 x1 = *reinterpret_cast<const float4*>(src + 4);
      half8 hh;
      hh[0] = (_Float16)x0.x; hh[1] = (_Float16)x0.y;
      hh[2] = (_Float16)x0.z; hh[3] = (_Float16)x0.w;
      hh[4] = (_Float16)x1.x; hh[5] = (_Float16)x1.y;
      hh[6] = (_Float16)x1.z; hh[7] = (_Float16)x1.w;
      int m = row >> 4;
      int lane_s = lhi | (row & 15);
      *reinterpret_cast<half8*>(&Alds[(((m * 8) + kt_s) * 64 + lane_s) * 8]) = hh;
    }
  }
  __syncthreads();

  const half8* bp = reinterpret_cast<const half8*>(Bperm);
  const int ntb = wave * 4;

  f32x4 acc[4][4];
#pragma unroll
  for (int m = 0; m < 4; ++m)
#pragma unroll
    for (int n = 0; n < 4; ++n) acc[m][n] = (f32x4){0.f, 0.f, 0.f, 0.f};

  half8 bB[2][4];
#pragma unroll
  for (int n = 0; n < 4; ++n) bB[0][n] = bp[((ntb + n) * 8 + 0) * 64 + lane];

#pragma unroll
  for (int kt = 0; kt < 8; ++kt) {
    if (kt < 7) {
#pragma unroll
      for (int n = 0; n < 4; ++n)
        bB[(kt + 1) & 1][n] = bp[((ntb + n) * 8 + kt + 1) * 64 + lane];
    }
    half8 a[4];
#pragma unroll
    for (int m = 0; m < 4; ++m)
      a[m] = *reinterpret_cast<const half8*>(&Alds[((m * 8 + kt) * 64 + lane) * 8]);
#pragma unroll
    for (int m = 0; m < 4; ++m)
#pragma unroll
      for (int n = 0; n < 4; ++n)
        acc[m][n] = __builtin_amdgcn_mfma_f32_16x16x32_f16(
            a[m], bB[kt & 1][n], acc[m][n], 0, 0, 0);
  }

  // ---- score epilogue (lean tanh) ----
  float hpv[4], vg[4];
#pragma unroll
  for (int n = 0; n < 4; ++n) {
    int g = (ntb + n) * 16 + r;
    hpv[n] = hid_proj[b * H + g];
    vg[n] = v[g];
  }
#pragma unroll
  for (int m = 0; m < 4; ++m) {
#pragma unroll
    for (int i = 0; i < 4; ++i) {
      float s = 0.f;
#pragma unroll
      for (int n = 0; n < 4; ++n)
        s = fmaf(vg[n], tanh_fast(acc[m][n][i] + hpv[n]), s);
      s += __shfl_xor(s, 1);
      s += __shfl_xor(s, 2);
      s += __shfl_xor(s, 4);
      s += __shfl_xor(s, 8);
      if (r == 0) spart[wave][m * 16 + grp * 4 + i] = s;
    }
  }
  __syncthreads();

  // ---- wave 0: finalize scores, chunk-local softmax stats ----
  if (tid < 64) {
    float sv = spart[0][tid] + spart[1][tid] + spart[2][tid] + spart[3][tid];
    scores[(size_t)b * T + t0 + tid] = sv;
    float mc = sv;
#pragma unroll
    for (int off = 32; off > 0; off >>= 1) mc = fmaxf(mc, __shfl_xor(mc, off));
    float w = __expf(sv - mc);
    wbuf[tid] = w;
    float lc = w;
#pragma unroll
    for (int off = 32; off > 0; off >>= 1) lc += __shfl_xor(lc, off);
    if (tid == 0) {
      mbuf[b * NCHUNK + chunk] = mc;
      lbuf[b * NCHUNK + chunk] = lc;
    }
  }
  __syncthreads();

  // ---- partial context: wave handles kt = 2*wave, 2*wave+1 ----
#pragma unroll
  for (int kk = 0; kk < 2; ++kk) {
    const int kt = wave * 2 + kk;
    float cacc[8];
#pragma unroll
    for (int j = 0; j < 8; ++j) cacc[j] = 0.f;
#pragma unroll
    for (int m = 0; m < 4; ++m) {
      half8 a = *reinterpret_cast<const half8*>(
          &Alds[((m * 8 + kt) * 64 + lane) * 8]);
      float wt = wbuf[m * 16 + r];
#pragma unroll
      for (int j = 0; j < 8; ++j) cacc[j] = fmaf(wt, (float)a[j], cacc[j]);
    }
    // reduce over r (16 lanes per grp-group)
#pragma unroll
    for (int j = 0; j < 8; ++j) {
      float s = cacc[j];
      s += __shfl_xor(s, 1);
      s += __shfl_xor(s, 2);
      s += __shfl_xor(s, 4);
      s += __shfl_xor(s, 8);
      cacc[j] = s;
    }
    if (r == 0) {
      float4 lo = {cacc[0], cacc[1], cacc[2], cacc[3]};
      float4 hi = {cacc[4], cacc[5], cacc[6], cacc[7]};
      float* dst = cp + ((size_t)chunk * B + b) * H + kt * 32 + grp * 8;
      *reinterpret_cast<float4*>(dst) = lo;
      *reinterpret_cast<float4*>(dst + 4) = hi;
    }
  }
}

// ---------------- K3: softmax over T per b (attn_weights output) ----
__global__ __launch_bounds__(256) void k3_softmax(
    const float* __restrict__ scores, float* __restrict__ attn_out) {
  int b = blockIdx.x;
  int tid = threadIdx.x;
  float vals[16];
  const float4* sp = reinterpret_cast<const float4*>(scores + (size_t)b * T);
#pragma unroll
  for (int i = 0; i < 4; ++i) {
    float4 x = sp[i * 256 + tid];
    vals[i * 4 + 0] = x.x; vals[i * 4 + 1] = x.y;
    vals[i * 4 + 2] = x.z; vals[i * 4 + 3] = x.w;
  }
  float m = -INFINITY;
#pragma unroll
  for (int i = 0; i < 16; ++i) m = fmaxf(m, vals[i]);
  for (int off = 32; off > 0; off >>= 1) m = fmaxf(m, __shfl_xor(m, off));
  __shared__ float redm[4];
  int wave = tid >> 6, lane = tid & 63;
  if (lane == 0) redm[wave] = m;
  __syncthreads();
  m = fmaxf(fmaxf(redm[0], redm[1]), fmaxf(redm[2], redm[3]));
  float s = 0.f;
#pragma unroll
  for (int i = 0; i < 16; ++i) {
    vals[i] = expf(vals[i] - m);
    s += vals[i];
  }
  for (int off = 32; off > 0; off >>= 1) s += __shfl_xor(s, off);
  __shared__ float reds[4];
  if (lane == 0) reds[wave] = s;
  __syncthreads();
  s = reds[0] + reds[1] + reds[2] + reds[3];
  float inv = 1.f / s;
  float4* op = reinterpret_cast<float4*>(attn_out + (size_t)b * T);
#pragma unroll
  for (int i = 0; i < 4; ++i) {
    float4 x;
    x.x = vals[i * 4 + 0] * inv; x.y = vals[i * 4 + 1] * inv;
    x.z = vals[i * 4 + 2] * inv; x.w = vals[i * 4 + 3] * inv;
    op[i * 256 + tid] = x;
  }
}

// ---------------- K5: recombine chunks -> context, then pre-linear ----
__global__ __launch_bounds__(256) void k5_prelinear(
    const float* __restrict__ cp, const float* __restrict__ mbuf,
    const float* __restrict__ lbuf, const float* __restrict__ motion,
    const float* __restrict__ pre_W, const float* __restrict__ pre_b,
    float* __restrict__ xpre) {
  int b = blockIdx.x;
  int g = threadIdx.x;
  __shared__ float mc[NCHUNK], lc[NCHUNK];
  __shared__ __align__(16) float cm[D + H];
  if (g < NCHUNK) {
    mc[g] = mbuf[b * NCHUNK + g];
    lc[g] = lbuf[b * NCHUNK + g];
  }
  __syncthreads();
  float m = -INFINITY;
#pragma unroll 8
  for (int c = 0; c < NCHUNK; ++c) m = fmaxf(m, mc[c]);
  float l = 0.f, ctx = 0.f;
#pragma unroll 4
  for (int c = 0; c < NCHUNK; ++c) {
    float al = __expf(mc[c] - m);
    l += lc[c] * al;
    ctx += al * cp[((size_t)c * B + b) * H + g];
  }
  cm[D + g] = ctx / l;
  if (g < D) cm[g] = motion[b * D + g];
  __syncthreads();
  const float4* cm4 = reinterpret_cast<const float4*>(cm);
  const float4* wr = reinterpret_cast<const float4*>(pre_W + (size_t)g * (D + H));
  float acc = pre_b[g];
#pragma unroll 8
  for (int j = 0; j < (D + H) / 4; ++j) {
    float4 w = wr[j], x = cm4[j];
    acc += w.x * x.x + w.y * x.y + w.z * x.z + w.w * x.w;
  }
  xpre[b * H + g] = acc;
}

// ---------------- K5b: batchnorm + relu ----
__global__ __launch_bounds__(256) void k5b_bn(
    const float* __restrict__ xpre, const float* __restrict__ gamma,
    const float* __restrict__ beta, float* __restrict__ xn) {
  int g = threadIdx.x;
  float mu = 0.f;
  for (int b = 0; b < B; ++b) mu += xpre[b * H + g];
  mu *= (1.f / B);
  float var = 0.f;
  for (int b = 0; b < B; ++b) {
    float d = xpre[b * H + g] - mu;
    var += d * d;
  }
  var *= (1.f / B);
  float sc = gamma[g] * rsqrtf(var + EPS);
  float bi = beta[g];
  for (int b = 0; b < B; ++b) {
    float y = (xpre[b * H + g] - mu) * sc + bi;
    xn[b * H + g] = fmaxf(y, 0.f);
  }
}

// ---------------- K6: GRU cell + output projection ----
__global__ __launch_bounds__(256) void k6_gru_out(
    const float* __restrict__ xn, const float* __restrict__ gh,
    const float* __restrict__ W_ih, const float* __restrict__ b_ih,
    const float* __restrict__ last_hidden, const float* __restrict__ out_W,
    const float* __restrict__ out_b, float* __restrict__ out_output,
    float* __restrict__ out_hidden) {
  int b = blockIdx.x;
  int g = threadIdx.x;
  __shared__ __align__(16) float xr[H];
  __shared__ __align__(16) float hn[H];
  xr[g] = xn[b * H + g];
  __syncthreads();
  const float4* xr4 = reinterpret_cast<const float4*>(xr);
  float gi[3];
#pragma unroll
  for (int k = 0; k < 3; ++k) {
    int row = k * H + g;
    const float4* wr = reinterpret_cast<const float4*>(W_ih + (size_t)row * H);
    float a = b_ih[row];
#pragma unroll 8
    for (int h4 = 0; h4 < H / 4; ++h4) {
      float4 w = wr[h4], x = xr4[h4];
      a += w.x * x.x + w.y * x.y + w.z * x.z + w.w * x.w;
    }
    gi[k] = a;
  }
  float hr = gh[(size_t)b * 3 * H + g];
  float hz = gh[(size_t)b * 3 * H + H + g];
  float hnn = gh[(size_t)b * 3 * H + 2 * H + g];
  float r = 1.f / (1.f + expf(-(gi[0] + hr)));
  float z = 1.f / (1.f + expf(-(gi[1] + hz)));
  float n = tanhf(gi[2] + r * hnn);
  float hprev = last_hidden[b * H + g];
  float hnew = (1.f - z) * n + z * hprev;
  out_hidden[b * H + g] = hnew;
  hn[g] = hnew;
  __syncthreads();
  if (g < O) {
    const float4* hn4 = reinterpret_cast<const float4*>(hn);
    const float4* wr = reinterpret_cast<const float4*>(out_W + (size_t)g * H);
    float a = out_b[g];
#pragma unroll 8
    for (int h4 = 0; h4 < H / 4; ++h4) {
      float4 w = wr[h4], x = hn4[h4];
      a += w.x * x.x + w.y * x.y + w.z * x.z + w.w * x.w;
    }
    out_output[b * O + g] = a;
  }
}

extern "C" void kernel_launch(void* const* d_in, const int* in_sizes, int n_in,
                              void* d_out, int out_size, void* d_ws,
                              size_t ws_size, hipStream_t stream) {
  (void)in_sizes; (void)n_in; (void)out_size; (void)ws_size;
  const float* motion      = (const float*)d_in[0];
  const float* last_hidden = (const float*)d_in[1];
  const float* enc         = (const float*)d_in[2];
  const float* attn_W      = (const float*)d_in[3];
  const float* attn_b      = (const float*)d_in[4];
  const float* v           = (const float*)d_in[5];
  const float* pre_W       = (const float*)d_in[6];
  const float* pre_b       = (const float*)d_in[7];
  const float* bn_g        = (const float*)d_in[8];
  const float* bn_b        = (const float*)d_in[9];
  const float* W_ih        = (const float*)d_in[10];
  const float* b_ih        = (const float*)d_in[11];
  const float* W_hh        = (const float*)d_in[12];
  const float* b_hh        = (const float*)d_in[13];
  const float* out_W       = (const float*)d_in[14];
  const float* out_b       = (const float*)d_in[15];

  float* out = (float*)d_out;
  float* out_output = out;
  float* out_hidden = out + B * O;
  float* out_attn   = out + B * O + B * H;

  float* ws = (float*)d_ws;
  float* sc   = ws;                                  // B*T
  float* cp   = sc + (size_t)B * T;                  // NCHUNK*B*H
  float* mbuf = cp + (size_t)NCHUNK * B * H;         // B*NCHUNK
  float* lbuf = mbuf + (size_t)B * NCHUNK;           // B*NCHUNK
  float* hp   = lbuf + (size_t)B * NCHUNK;           // B*H
  float* gh   = hp + (size_t)B * H;                  // 3*B*H
  float* xp   = gh + (size_t)3 * B * H;              // B*H
  float* xn   = xp + (size_t)B * H;                  // B*H
  _Float16* Bperm = (_Float16*)(xn + (size_t)B * H); // H*H f16

  k0_permW<<<256, 256, 0, stream>>>(attn_W, Bperm);
  k1_hidproj_gh<<<B, 256, 0, stream>>>(last_hidden, attn_W, attn_b, W_hh, b_hh,
                                       hp, gh);
  k2_fused<<<dim3(NCHUNK, B), 256, 0, stream>>>(enc, Bperm, hp, v, sc, cp,
                                                mbuf, lbuf);
  k3_softmax<<<B, 256, 0, stream>>>(sc, out_attn);
  k5_prelinear<<<B, 256, 0, stream>>>(cp, mbuf, lbuf, motion, pre_W, pre_b, xp);
  k5b_bn<<<1, 256, 0, stream>>>(xp, bn_g, bn_b, xn);
  k6_gru_out<<<B, 256, 0, stream>>>(xn, gh, W_ih, b_ih, last_hidden, out_W,
                                    out_b, out_output, out_hidden);
}

// Round 22
// 185.716 us; speedup vs baseline: 1.0452x; 1.0452x over previous
//
#include <hip/hip_runtime.h>
#include <math.h>

#define B 64
#define T 4096
#define H 256
#define D 128
#define O 128
#define EPS 1e-5f

#define NCHUNK 64    // T/64 score chunks (= k2 grid.x)

typedef _Float16 half8 __attribute__((ext_vector_type(8)));
typedef float f32x4 __attribute__((ext_vector_type(4)));

__device__ __forceinline__ float rcp_fast(float x) {
  float r;
  asm("v_rcp_f32 %0, %1" : "=v"(r) : "v"(x));
  return r;
}

// lean tanh: 1 - 2*rcp(exp(2x)+1); exp overflow -> 1, underflow -> -1
__device__ __forceinline__ float tanh_fast(float x) {
  return fmaf(-2.f, rcp_fast(__expf(2.f * x) + 1.f), 1.f);
}

// ---------------- K0: permute W_e into f16 MFMA-fragment order ----
__global__ __launch_bounds__(256) void k0_permW(const float* __restrict__ attn_W,
                                               _Float16* __restrict__ Bperm) {
  int idx = blockIdx.x * 256 + threadIdx.x;
  int j = idx & 7;
  int l = (idx >> 3) & 63;
  int kt = (idx >> 9) & 7;
  int nt = idx >> 12;
  int g = nt * 16 + (l & 15);
  int k = kt * 32 + ((l >> 4) << 3) + j;
  Bperm[idx] = (_Float16)attn_W[(size_t)g * (2 * H) + H + k];
}

// ---------------- K1 ----
__global__ __launch_bounds__(256) void k1_hidproj_gh(
    const float* __restrict__ last_hidden, const float* __restrict__ attn_W,
    const float* __restrict__ attn_b, const float* __restrict__ W_hh,
    const float* __restrict__ b_hh, float* __restrict__ hid_proj,
    float* __restrict__ gh) {
  int b = blockIdx.x;
  int g = threadIdx.x;
  __shared__ __align__(16) float hp[H];
  hp[g] = last_hidden[b * H + g];
  __syncthreads();
  const float4* hp4 = reinterpret_cast<const float4*>(hp);
  const float4* wr = reinterpret_cast<const float4*>(attn_W + (size_t)g * (2 * H));
  float acc = attn_b[g];
#pragma unroll 8
  for (int h4 = 0; h4 < H / 4; ++h4) {
    float4 w = wr[h4], x = hp4[h4];
    acc += w.x * x.x + w.y * x.y + w.z * x.z + w.w * x.w;
  }
  hid_proj[b * H + g] = acc;
#pragma unroll
  for (int k = 0; k < 3; ++k) {
    int row = k * H + g;
    const float4* whr = reinterpret_cast<const float4*>(W_hh + (size_t)row * H);
    float a2 = b_hh[row];
#pragma unroll 8
    for (int h4 = 0; h4 < H / 4; ++h4) {
      float4 w = whr[h4], x = hp4[h4];
      a2 += w.x * x.x + w.y * x.y + w.z * x.z + w.w * x.w;
    }
    gh[(size_t)b * (3 * H) + row] = a2;
  }
}

// ======== K2 fused: scores (MFMA) + chunk-softmax + partial context ========
// R20-verified structure (best total: 186.1 us). TT=64, 256thr, (256,2), LDS
// f16 frags, conflict-free staging; after scores, chunk-local softmax stats
// and partial context accumulated from the SAME LDS fragments (no k4 pass).
__global__ __launch_bounds__(256, 2) void k2_fused(
    const float* __restrict__ enc, const _Float16* __restrict__ Bperm,
    const float* __restrict__ hid_proj, const float* __restrict__ v,
    float* __restrict__ scores, float* __restrict__ cp,
    float* __restrict__ mbuf, float* __restrict__ lbuf) {
  const int b = blockIdx.y;
  const int chunk = blockIdx.x;
  const int t0 = chunk * 64;
  const int tid = threadIdx.x;
  const int wave = tid >> 6;
  const int lane = tid & 63;
  const int r = lane & 15;
  const int grp = lane >> 4;

  __shared__ __align__(16) _Float16 Alds[4 * 8 * 64 * 8];  // 32KB
  __shared__ float spart[4][64];
  __shared__ float wbuf[64];

  // ---- stage enc tile -> f16 fragment order (conflict-free writes) ----
  {
    const int rbase = tid & 7;
    const int kg = tid >> 3;
    const int kt_s = kg >> 2;
    const int lhi = (kg & 3) << 4;
#pragma unroll
    for (int i = 0; i < 8; ++i) {
      int row = i * 8 + rbase;
      const float* src = enc + ((size_t)(t0 + row) * B + b) * H + kg * 8;
      float4 x0 = *reinterpret_cast<const float4*>(src);
      float4 x1 = *reinterpret_cast<const float4*>(src + 4);
      half8 hh;
      hh[0] = (_Float16)x0.x; hh[1] = (_Float16)x0.y;
      hh[2] = (_Float16)x0.z; hh[3] = (_Float16)x0.w;
      hh[4] = (_Float16)x1.x; hh[5] = (_Float16)x1.y;
      hh[6] = (_Float16)x1.z; hh[7] = (_Float16)x1.w;
      int m = row >> 4;
      int lane_s = lhi | (row & 15);
      *reinterpret_cast<half8*>(&Alds[(((m * 8) + kt_s) * 64 + lane_s) * 8]) = hh;
    }
  }
  __syncthreads();

  const half8* bp = reinterpret_cast<const half8*>(Bperm);
  const int ntb = wave * 4;

  f32x4 acc[4][4];
#pragma unroll
  for (int m = 0; m < 4; ++m)
#pragma unroll
    for (int n = 0; n < 4; ++n) acc[m][n] = (f32x4){0.f, 0.f, 0.f, 0.f};

  half8 bB[2][4];
#pragma unroll
  for (int n = 0; n < 4; ++n) bB[0][n] = bp[((ntb + n) * 8 + 0) * 64 + lane];

#pragma unroll
  for (int kt = 0; kt < 8; ++kt) {
    if (kt < 7) {
#pragma unroll
      for (int n = 0; n < 4; ++n)
        bB[(kt + 1) & 1][n] = bp[((ntb + n) * 8 + kt + 1) * 64 + lane];
    }
    half8 a[4];
#pragma unroll
    for (int m = 0; m < 4; ++m)
      a[m] = *reinterpret_cast<const half8*>(&Alds[((m * 8 + kt) * 64 + lane) * 8]);
#pragma unroll
    for (int m = 0; m < 4; ++m)
#pragma unroll
      for (int n = 0; n < 4; ++n)
        acc[m][n] = __builtin_amdgcn_mfma_f32_16x16x32_f16(
            a[m], bB[kt & 1][n], acc[m][n], 0, 0, 0);
  }

  // ---- score epilogue (lean tanh) ----
  float hpv[4], vg[4];
#pragma unroll
  for (int n = 0; n < 4; ++n) {
    int g = (ntb + n) * 16 + r;
    hpv[n] = hid_proj[b * H + g];
    vg[n] = v[g];
  }
#pragma unroll
  for (int m = 0; m < 4; ++m) {
#pragma unroll
    for (int i = 0; i < 4; ++i) {
      float s = 0.f;
#pragma unroll
      for (int n = 0; n < 4; ++n)
        s = fmaf(vg[n], tanh_fast(acc[m][n][i] + hpv[n]), s);
      s += __shfl_xor(s, 1);
      s += __shfl_xor(s, 2);
      s += __shfl_xor(s, 4);
      s += __shfl_xor(s, 8);
      if (r == 0) spart[wave][m * 16 + grp * 4 + i] = s;
    }
  }
  __syncthreads();

  // ---- wave 0: finalize scores, chunk-local softmax stats ----
  if (tid < 64) {
    float sv = spart[0][tid] + spart[1][tid] + spart[2][tid] + spart[3][tid];
    scores[(size_t)b * T + t0 + tid] = sv;
    float mc = sv;
#pragma unroll
    for (int off = 32; off > 0; off >>= 1) mc = fmaxf(mc, __shfl_xor(mc, off));
    float w = __expf(sv - mc);
    wbuf[tid] = w;
    float lc = w;
#pragma unroll
    for (int off = 32; off > 0; off >>= 1) lc += __shfl_xor(lc, off);
    if (tid == 0) {
      mbuf[b * NCHUNK + chunk] = mc;
      lbuf[b * NCHUNK + chunk] = lc;
    }
  }
  __syncthreads();

  // ---- partial context: wave handles kt = 2*wave, 2*wave+1 ----
#pragma unroll
  for (int kk = 0; kk < 2; ++kk) {
    const int kt = wave * 2 + kk;
    float cacc[8];
#pragma unroll
    for (int j = 0; j < 8; ++j) cacc[j] = 0.f;
#pragma unroll
    for (int m = 0; m < 4; ++m) {
      half8 a = *reinterpret_cast<const half8*>(
          &Alds[((m * 8 + kt) * 64 + lane) * 8]);
      float wt = wbuf[m * 16 + r];
#pragma unroll
      for (int j = 0; j < 8; ++j) cacc[j] = fmaf(wt, (float)a[j], cacc[j]);
    }
    // reduce over r (16 lanes per grp-group)
#pragma unroll
    for (int j = 0; j < 8; ++j) {
      float s = cacc[j];
      s += __shfl_xor(s, 1);
      s += __shfl_xor(s, 2);
      s += __shfl_xor(s, 4);
      s += __shfl_xor(s, 8);
      cacc[j] = s;
    }
    if (r == 0) {
      float4 lo = {cacc[0], cacc[1], cacc[2], cacc[3]};
      float4 hi = {cacc[4], cacc[5], cacc[6], cacc[7]};
      float* dst = cp + ((size_t)chunk * B + b) * H + kt * 32 + grp * 8;
      *reinterpret_cast<float4*>(dst) = lo;
      *reinterpret_cast<float4*>(dst + 4) = hi;
    }
  }
}

// ---------------- K3: softmax over T per b (attn_weights output) ----
__global__ __launch_bounds__(256) void k3_softmax(
    const float* __restrict__ scores, float* __restrict__ attn_out) {
  int b = blockIdx.x;
  int tid = threadIdx.x;
  float vals[16];
  const float4* sp = reinterpret_cast<const float4*>(scores + (size_t)b * T);
#pragma unroll
  for (int i = 0; i < 4; ++i) {
    float4 x = sp[i * 256 + tid];
    vals[i * 4 + 0] = x.x; vals[i * 4 + 1] = x.y;
    vals[i * 4 + 2] = x.z; vals[i * 4 + 3] = x.w;
  }
  float m = -INFINITY;
#pragma unroll
  for (int i = 0; i < 16; ++i) m = fmaxf(m, vals[i]);
  for (int off = 32; off > 0; off >>= 1) m = fmaxf(m, __shfl_xor(m, off));
  __shared__ float redm[4];
  int wave = tid >> 6, lane = tid & 63;
  if (lane == 0) redm[wave] = m;
  __syncthreads();
  m = fmaxf(fmaxf(redm[0], redm[1]), fmaxf(redm[2], redm[3]));
  float s = 0.f;
#pragma unroll
  for (int i = 0; i < 16; ++i) {
    vals[i] = expf(vals[i] - m);
    s += vals[i];
  }
  for (int off = 32; off > 0; off >>= 1) s += __shfl_xor(s, off);
  __shared__ float reds[4];
  if (lane == 0) reds[wave] = s;
  __syncthreads();
  s = reds[0] + reds[1] + reds[2] + reds[3];
  float inv = 1.f / s;
  float4* op = reinterpret_cast<float4*>(attn_out + (size_t)b * T);
#pragma unroll
  for (int i = 0; i < 4; ++i) {
    float4 x;
    x.x = vals[i * 4 + 0] * inv; x.y = vals[i * 4 + 1] * inv;
    x.z = vals[i * 4 + 2] * inv; x.w = vals[i * 4 + 3] * inv;
    op[i * 256 + tid] = x;
  }
}

// ---------------- K5: recombine chunks -> context, then pre-linear ----
__global__ __launch_bounds__(256) void k5_prelinear(
    const float* __restrict__ cp, const float* __restrict__ mbuf,
    const float* __restrict__ lbuf, const float* __restrict__ motion,
    const float* __restrict__ pre_W, const float* __restrict__ pre_b,
    float* __restrict__ xpre) {
  int b = blockIdx.x;
  int g = threadIdx.x;
  __shared__ float mc[NCHUNK], lc[NCHUNK];
  __shared__ __align__(16) float cm[D + H];
  if (g < NCHUNK) {
    mc[g] = mbuf[b * NCHUNK + g];
    lc[g] = lbuf[b * NCHUNK + g];
  }
  __syncthreads();
  float m = -INFINITY;
#pragma unroll 8
  for (int c = 0; c < NCHUNK; ++c) m = fmaxf(m, mc[c]);
  float l = 0.f, ctx = 0.f;
#pragma unroll 4
  for (int c = 0; c < NCHUNK; ++c) {
    float al = __expf(mc[c] - m);
    l += lc[c] * al;
    ctx += al * cp[((size_t)c * B + b) * H + g];
  }
  cm[D + g] = ctx / l;
  if (g < D) cm[g] = motion[b * D + g];
  __syncthreads();
  const float4* cm4 = reinterpret_cast<const float4*>(cm);
  const float4* wr = reinterpret_cast<const float4*>(pre_W + (size_t)g * (D + H));
  float acc = pre_b[g];
#pragma unroll 8
  for (int j = 0; j < (D + H) / 4; ++j) {
    float4 w = wr[j], x = cm4[j];
    acc += w.x * x.x + w.y * x.y + w.z * x.z + w.w * x.w;
  }
  xpre[b * H + g] = acc;
}

// ---------------- K5b: batchnorm + relu ----
__global__ __launch_bounds__(256) void k5b_bn(
    const float* __restrict__ xpre, const float* __restrict__ gamma,
    const float* __restrict__ beta, float* __restrict__ xn) {
  int g = threadIdx.x;
  float mu = 0.f;
  for (int b = 0; b < B; ++b) mu += xpre[b * H + g];
  mu *= (1.f / B);
  float var = 0.f;
  for (int b = 0; b < B; ++b) {
    float d = xpre[b * H + g] - mu;
    var += d * d;
  }
  var *= (1.f / B);
  float sc = gamma[g] * rsqrtf(var + EPS);
  float bi = beta[g];
  for (int b = 0; b < B; ++b) {
    float y = (xpre[b * H + g] - mu) * sc + bi;
    xn[b * H + g] = fmaxf(y, 0.f);
  }
}

// ---------------- K6: GRU cell + output projection ----
__global__ __launch_bounds__(256) void k6_gru_out(
    const float* __restrict__ xn, const float* __restrict__ gh,
    const float* __restrict__ W_ih, const float* __restrict__ b_ih,
    const float* __restrict__ last_hidden, const float* __restrict__ out_W,
    const float* __restrict__ out_b, float* __restrict__ out_output,
    float* __restrict__ out_hidden) {
  int b = blockIdx.x;
  int g = threadIdx.x;
  __shared__ __align__(16) float xr[H];
  __shared__ __align__(16) float hn[H];
  xr[g] = xn[b * H + g];
  __syncthreads();
  const float4* xr4 = reinterpret_cast<const float4*>(xr);
  float gi[3];
#pragma unroll
  for (int k = 0; k < 3; ++k) {
    int row = k * H + g;
    const float4* wr = reinterpret_cast<const float4*>(W_ih + (size_t)row * H);
    float a = b_ih[row];
#pragma unroll 8
    for (int h4 = 0; h4 < H / 4; ++h4) {
      float4 w = wr[h4], x = xr4[h4];
      a += w.x * x.x + w.y * x.y + w.z * x.z + w.w * x.w;
    }
    gi[k] = a;
  }
  float hr = gh[(size_t)b * 3 * H + g];
  float hz = gh[(size_t)b * 3 * H + H + g];
  float hnn = gh[(size_t)b * 3 * H + 2 * H + g];
  float r = 1.f / (1.f + expf(-(gi[0] + hr)));
  float z = 1.f / (1.f + expf(-(gi[1] + hz)));
  float n = tanhf(gi[2] + r * hnn);
  float hprev = last_hidden[b * H + g];
  float hnew = (1.f - z) * n + z * hprev;
  out_hidden[b * H + g] = hnew;
  hn[g] = hnew;
  __syncthreads();
  if (g < O) {
    const float4* hn4 = reinterpret_cast<const float4*>(hn);
    const float4* wr = reinterpret_cast<const float4*>(out_W + (size_t)g * H);
    float a = out_b[g];
#pragma unroll 8
    for (int h4 = 0; h4 < H / 4; ++h4) {
      float4 w = wr[h4], x = hn4[h4];
      a += w.x * x.x + w.y * x.y + w.z * x.z + w.w * x.w;
    }
    out_output[b * O + g] = a;
  }
}

extern "C" void kernel_launch(void* const* d_in, const int* in_sizes, int n_in,
                              void* d_out, int out_size, void* d_ws,
                              size_t ws_size, hipStream_t stream) {
  (void)in_sizes; (void)n_in; (void)out_size; (void)ws_size;
  const float* motion      = (const float*)d_in[0];
  const float* last_hidden = (const float*)d_in[1];
  const float* enc         = (const float*)d_in[2];
  const float* attn_W      = (const float*)d_in[3];
  const float* attn_b      = (const float*)d_in[4];
  const float* v           = (const float*)d_in[5];
  const float* pre_W       = (const float*)d_in[6];
  const float* pre_b       = (const float*)d_in[7];
  const float* bn_g        = (const float*)d_in[8];
  const float* bn_b        = (const float*)d_in[9];
  const float* W_ih        = (const float*)d_in[10];
  const float* b_ih        = (const float*)d_in[11];
  const float* W_hh        = (const float*)d_in[12];
  const float* b_hh        = (const float*)d_in[13];
  const float* out_W       = (const float*)d_in[14];
  const float* out_b       = (const float*)d_in[15];

  float* out = (float*)d_out;
  float* out_output = out;
  float* out_hidden = out + B * O;
  float* out_attn   = out + B * O + B * H;

  float* ws = (float*)d_ws;
  float* sc   = ws;                                  // B*T
  float* cp   = sc + (size_t)B * T;                  // NCHUNK*B*H
  float* mbuf = cp + (size_t)NCHUNK * B * H;         // B*NCHUNK
  float* lbuf = mbuf + (size_t)B * NCHUNK;           // B*NCHUNK
  float* hp   = lbuf + (size_t)B * NCHUNK;           // B*H
  float* gh   = hp + (size_t)B * H;                  // 3*B*H
  float* xp   = gh + (size_t)3 * B * H;              // B*H
  float* xn   = xp + (size_t)B * H;                  // B*H
  _Float16* Bperm = (_Float16*)(xn + (size_t)B * H); // H*H f16

  k0_permW<<<256, 256, 0, stream>>>(attn_W, Bperm);
  k1_hidproj_gh<<<B, 256, 0, stream>>>(last_hidden, attn_W, attn_b, W_hh, b_hh,
                                       hp, gh);
  k2_fused<<<dim3(NCHUNK, B), 256, 0, stream>>>(enc, Bperm, hp, v, sc, cp,
                                                mbuf, lbuf);
  k3_softmax<<<B, 256, 0, stream>>>(sc, out_attn);
  k5_prelinear<<<B, 256, 0, stream>>>(cp, mbuf, lbuf, motion, pre_W, pre_b, xp);
  k5b_bn<<<1, 256, 0, stream>>>(xp, bn_g, bn_b, xn);
  k6_gru_out<<<B, 256, 0, stream>>>(xn, gh, W_ih, b_ih, last_hidden, out_W,
                                    out_b, out_output, out_hidden);
}

// Round 23
// 182.503 us; speedup vs baseline: 1.0636x; 1.0176x over previous
//
#include <hip/hip_runtime.h>
#include <math.h>

#define B 64
#define T 4096
#define H 256
#define D 128
#define O 128
#define EPS 1e-5f

#define NCHUNK 64    // T/64 score chunks (= k2 grid.x)

typedef _Float16 half8 __attribute__((ext_vector_type(8)));
typedef float f32x4 __attribute__((ext_vector_type(4)));

__device__ __forceinline__ float rcp_fast(float x) {
  float r;
  asm("v_rcp_f32 %0, %1" : "=v"(r) : "v"(x));
  return r;
}

// lean tanh: 1 - 2*rcp(exp(2x)+1); exp overflow -> 1, underflow -> -1
__device__ __forceinline__ float tanh_fast(float x) {
  return fmaf(-2.f, rcp_fast(__expf(2.f * x) + 1.f), 1.f);
}

// ---------------- K0: permute W_e into f16 MFMA-fragment order ----
__global__ __launch_bounds__(256) void k0_permW(const float* __restrict__ attn_W,
                                               _Float16* __restrict__ Bperm) {
  int idx = blockIdx.x * 256 + threadIdx.x;
  int j = idx & 7;
  int l = (idx >> 3) & 63;
  int kt = (idx >> 9) & 7;
  int nt = idx >> 12;
  int g = nt * 16 + (l & 15);
  int k = kt * 32 + ((l >> 4) << 3) + j;
  Bperm[idx] = (_Float16)attn_W[(size_t)g * (2 * H) + H + k];
}

// ---------------- K1 ----
__global__ __launch_bounds__(256) void k1_hidproj_gh(
    const float* __restrict__ last_hidden, const float* __restrict__ attn_W,
    const float* __restrict__ attn_b, const float* __restrict__ W_hh,
    const float* __restrict__ b_hh, float* __restrict__ hid_proj,
    float* __restrict__ gh) {
  int b = blockIdx.x;
  int g = threadIdx.x;
  __shared__ __align__(16) float hp[H];
  hp[g] = last_hidden[b * H + g];
  __syncthreads();
  const float4* hp4 = reinterpret_cast<const float4*>(hp);
  const float4* wr = reinterpret_cast<const float4*>(attn_W + (size_t)g * (2 * H));
  float acc = attn_b[g];
#pragma unroll 8
  for (int h4 = 0; h4 < H / 4; ++h4) {
    float4 w = wr[h4], x = hp4[h4];
    acc += w.x * x.x + w.y * x.y + w.z * x.z + w.w * x.w;
  }
  hid_proj[b * H + g] = acc;
#pragma unroll
  for (int k = 0; k < 3; ++k) {
    int row = k * H + g;
    const float4* whr = reinterpret_cast<const float4*>(W_hh + (size_t)row * H);
    float a2 = b_hh[row];
#pragma unroll 8
    for (int h4 = 0; h4 < H / 4; ++h4) {
      float4 w = whr[h4], x = hp4[h4];
      a2 += w.x * x.x + w.y * x.y + w.z * x.z + w.w * x.w;
    }
    gh[(size_t)b * (3 * H) + row] = a2;
  }
}

// ======== K2 fused: scores (MFMA) + chunk-softmax + partial context ========
// R20/R22-verified structure (banked best). TT=64, 256thr, (256,2), LDS
// f16 frags, conflict-free staging; after scores, chunk-local softmax stats
// and partial context accumulated from the SAME LDS fragments (no k4 pass).
__global__ __launch_bounds__(256, 2) void k2_fused(
    const float* __restrict__ enc, const _Float16* __restrict__ Bperm,
    const float* __restrict__ hid_proj, const float* __restrict__ v,
    float* __restrict__ scores, float* __restrict__ cp,
    float* __restrict__ mbuf, float* __restrict__ lbuf) {
  const int b = blockIdx.y;
  const int chunk = blockIdx.x;
  const int t0 = chunk * 64;
  const int tid = threadIdx.x;
  const int wave = tid >> 6;
  const int lane = tid & 63;
  const int r = lane & 15;
  const int grp = lane >> 4;

  __shared__ __align__(16) _Float16 Alds[4 * 8 * 64 * 8];  // 32KB
  __shared__ float spart[4][64];
  __shared__ float wbuf[64];

  // ---- stage enc tile -> f16 fragment order (conflict-free writes) ----
  {
    const int rbase = tid & 7;
    const int kg = tid >> 3;
    const int kt_s = kg >> 2;
    const int lhi = (kg & 3) << 4;
#pragma unroll
    for (int i = 0; i < 8; ++i) {
      int row = i * 8 + rbase;
      const float* src = enc + ((size_t)(t0 + row) * B + b) * H + kg * 8;
      float4 x0 = *reinterpret_cast<const float4*>(src);
      float4 x1 = *reinterpret_cast<const float4*>(src + 4);
      half8 hh;
      hh[0] = (_Float16)x0.x; hh[1] = (_Float16)x0.y;
      hh[2] = (_Float16)x0.z; hh[3] = (_Float16)x0.w;
      hh[4] = (_Float16)x1.x; hh[5] = (_Float16)x1.y;
      hh[6] = (_Float16)x1.z; hh[7] = (_Float16)x1.w;
      int m = row >> 4;
      int lane_s = lhi | (row & 15);
      *reinterpret_cast<half8*>(&Alds[(((m * 8) + kt_s) * 64 + lane_s) * 8]) = hh;
    }
  }
  __syncthreads();

  const half8* bp = reinterpret_cast<const half8*>(Bperm);
  const int ntb = wave * 4;

  f32x4 acc[4][4];
#pragma unroll
  for (int m = 0; m < 4; ++m)
#pragma unroll
    for (int n = 0; n < 4; ++n) acc[m][n] = (f32x4){0.f, 0.f, 0.f, 0.f};

  half8 bB[2][4];
#pragma unroll
  for (int n = 0; n < 4; ++n) bB[0][n] = bp[((ntb + n) * 8 + 0) * 64 + lane];

#pragma unroll
  for (int kt = 0; kt < 8; ++kt) {
    if (kt < 7) {
#pragma unroll
      for (int n = 0; n < 4; ++n)
        bB[(kt + 1) & 1][n] = bp[((ntb + n) * 8 + kt + 1) * 64 + lane];
    }
    half8 a[4];
#pragma unroll
    for (int m = 0; m < 4; ++m)
      a[m] = *reinterpret_cast<const half8*>(&Alds[((m * 8 + kt) * 64 + lane) * 8]);
#pragma unroll
    for (int m = 0; m < 4; ++m)
#pragma unroll
      for (int n = 0; n < 4; ++n)
        acc[m][n] = __builtin_amdgcn_mfma_f32_16x16x32_f16(
            a[m], bB[kt & 1][n], acc[m][n], 0, 0, 0);
  }

  // ---- score epilogue (lean tanh) ----
  float hpv[4], vg[4];
#pragma unroll
  for (int n = 0; n < 4; ++n) {
    int g = (ntb + n) * 16 + r;
    hpv[n] = hid_proj[b * H + g];
    vg[n] = v[g];
  }
#pragma unroll
  for (int m = 0; m < 4; ++m) {
#pragma unroll
    for (int i = 0; i < 4; ++i) {
      float s = 0.f;
#pragma unroll
      for (int n = 0; n < 4; ++n)
        s = fmaf(vg[n], tanh_fast(acc[m][n][i] + hpv[n]), s);
      s += __shfl_xor(s, 1);
      s += __shfl_xor(s, 2);
      s += __shfl_xor(s, 4);
      s += __shfl_xor(s, 8);
      if (r == 0) spart[wave][m * 16 + grp * 4 + i] = s;
    }
  }
  __syncthreads();

  // ---- wave 0: finalize scores, chunk-local softmax stats ----
  if (tid < 64) {
    float sv = spart[0][tid] + spart[1][tid] + spart[2][tid] + spart[3][tid];
    scores[(size_t)b * T + t0 + tid] = sv;
    float mc = sv;
#pragma unroll
    for (int off = 32; off > 0; off >>= 1) mc = fmaxf(mc, __shfl_xor(mc, off));
    float w = __expf(sv - mc);
    wbuf[tid] = w;
    float lc = w;
#pragma unroll
    for (int off = 32; off > 0; off >>= 1) lc += __shfl_xor(lc, off);
    if (tid == 0) {
      mbuf[b * NCHUNK + chunk] = mc;
      lbuf[b * NCHUNK + chunk] = lc;
    }
  }
  __syncthreads();

  // ---- partial context: wave handles kt = 2*wave, 2*wave+1 ----
#pragma unroll
  for (int kk = 0; kk < 2; ++kk) {
    const int kt = wave * 2 + kk;
    float cacc[8];
#pragma unroll
    for (int j = 0; j < 8; ++j) cacc[j] = 0.f;
#pragma unroll
    for (int m = 0; m < 4; ++m) {
      half8 a = *reinterpret_cast<const half8*>(
          &Alds[((m * 8 + kt) * 64 + lane) * 8]);
      float wt = wbuf[m * 16 + r];
#pragma unroll
      for (int j = 0; j < 8; ++j) cacc[j] = fmaf(wt, (float)a[j], cacc[j]);
    }
    // reduce over r (16 lanes per grp-group)
#pragma unroll
    for (int j = 0; j < 8; ++j) {
      float s = cacc[j];
      s += __shfl_xor(s, 1);
      s += __shfl_xor(s, 2);
      s += __shfl_xor(s, 4);
      s += __shfl_xor(s, 8);
      cacc[j] = s;
    }
    if (r == 0) {
      float4 lo = {cacc[0], cacc[1], cacc[2], cacc[3]};
      float4 hi = {cacc[4], cacc[5], cacc[6], cacc[7]};
      float* dst = cp + ((size_t)chunk * B + b) * H + kt * 32 + grp * 8;
      *reinterpret_cast<float4*>(dst) = lo;
      *reinterpret_cast<float4*>(dst + 4) = hi;
    }
  }
}

// ---------------- K3: softmax over T per b (attn_weights output) ----
__global__ __launch_bounds__(256) void k3_softmax(
    const float* __restrict__ scores, float* __restrict__ attn_out) {
  int b = blockIdx.x;
  int tid = threadIdx.x;
  float vals[16];
  const float4* sp = reinterpret_cast<const float4*>(scores + (size_t)b * T);
#pragma unroll
  for (int i = 0; i < 4; ++i) {
    float4 x = sp[i * 256 + tid];
    vals[i * 4 + 0] = x.x; vals[i * 4 + 1] = x.y;
    vals[i * 4 + 2] = x.z; vals[i * 4 + 3] = x.w;
  }
  float m = -INFINITY;
#pragma unroll
  for (int i = 0; i < 16; ++i) m = fmaxf(m, vals[i]);
  for (int off = 32; off > 0; off >>= 1) m = fmaxf(m, __shfl_xor(m, off));
  __shared__ float redm[4];
  int wave = tid >> 6, lane = tid & 63;
  if (lane == 0) redm[wave] = m;
  __syncthreads();
  m = fmaxf(fmaxf(redm[0], redm[1]), fmaxf(redm[2], redm[3]));
  float s = 0.f;
#pragma unroll
  for (int i = 0; i < 16; ++i) {
    vals[i] = expf(vals[i] - m);
    s += vals[i];
  }
  for (int off = 32; off > 0; off >>= 1) s += __shfl_xor(s, off);
  __shared__ float reds[4];
  if (lane == 0) reds[wave] = s;
  __syncthreads();
  s = reds[0] + reds[1] + reds[2] + reds[3];
  float inv = 1.f / s;
  float4* op = reinterpret_cast<float4*>(attn_out + (size_t)b * T);
#pragma unroll
  for (int i = 0; i < 4; ++i) {
    float4 x;
    x.x = vals[i * 4 + 0] * inv; x.y = vals[i * 4 + 1] * inv;
    x.z = vals[i * 4 + 2] * inv; x.w = vals[i * 4 + 3] * inv;
    op[i * 256 + tid] = x;
  }
}

// ---------------- K5: recombine chunks -> context, then pre-linear ----
__global__ __launch_bounds__(256) void k5_prelinear(
    const float* __restrict__ cp, const float* __restrict__ mbuf,
    const float* __restrict__ lbuf, const float* __restrict__ motion,
    const float* __restrict__ pre_W, const float* __restrict__ pre_b,
    float* __restrict__ xpre) {
  int b = blockIdx.x;
  int g = threadIdx.x;
  __shared__ float mc[NCHUNK], lc[NCHUNK];
  __shared__ __align__(16) float cm[D + H];
  if (g < NCHUNK) {
    mc[g] = mbuf[b * NCHUNK + g];
    lc[g] = lbuf[b * NCHUNK + g];
  }
  __syncthreads();
  float m = -INFINITY;
#pragma unroll 8
  for (int c = 0; c < NCHUNK; ++c) m = fmaxf(m, mc[c]);
  float l = 0.f, ctx = 0.f;
#pragma unroll 4
  for (int c = 0; c < NCHUNK; ++c) {
    float al = __expf(mc[c] - m);
    l += lc[c] * al;
    ctx += al * cp[((size_t)c * B + b) * H + g];
  }
  cm[D + g] = ctx / l;
  if (g < D) cm[g] = motion[b * D + g];
  __syncthreads();
  const float4* cm4 = reinterpret_cast<const float4*>(cm);
  const float4* wr = reinterpret_cast<const float4*>(pre_W + (size_t)g * (D + H));
  float acc = pre_b[g];
#pragma unroll 8
  for (int j = 0; j < (D + H) / 4; ++j) {
    float4 w = wr[j], x = cm4[j];
    acc += w.x * x.x + w.y * x.y + w.z * x.z + w.w * x.w;
  }
  xpre[b * H + g] = acc;
}

// ---------------- K6: batchnorm + relu + GRU cell + output projection ----
// k5b fused in: each block redundantly computes BN stats for its g values
// (64 coalesced L2-resident loads per loop; concurrent across 64 blocks,
// replacing the single-block serial k5b). Math order identical to k5b.
__global__ __launch_bounds__(256) void k6_bn_gru_out(
    const float* __restrict__ xpre, const float* __restrict__ gamma,
    const float* __restrict__ beta, const float* __restrict__ gh,
    const float* __restrict__ W_ih, const float* __restrict__ b_ih,
    const float* __restrict__ last_hidden, const float* __restrict__ out_W,
    const float* __restrict__ out_b, float* __restrict__ out_output,
    float* __restrict__ out_hidden) {
  int b = blockIdx.x;
  int g = threadIdx.x;
  __shared__ __align__(16) float xr[H];
  __shared__ __align__(16) float hn[H];

  // ---- BN stats over batch for feature g (same order as k5b) ----
  float mu = 0.f;
  for (int bb = 0; bb < B; ++bb) mu += xpre[bb * H + g];
  mu *= (1.f / B);
  float var = 0.f;
  for (int bb = 0; bb < B; ++bb) {
    float d = xpre[bb * H + g] - mu;
    var += d * d;
  }
  var *= (1.f / B);
  float sc = gamma[g] * rsqrtf(var + EPS);
  float bi = beta[g];
  float y = (xpre[b * H + g] - mu) * sc + bi;
  xr[g] = fmaxf(y, 0.f);
  __syncthreads();

  const float4* xr4 = reinterpret_cast<const float4*>(xr);
  float gi[3];
#pragma unroll
  for (int k = 0; k < 3; ++k) {
    int row = k * H + g;
    const float4* wr = reinterpret_cast<const float4*>(W_ih + (size_t)row * H);
    float a = b_ih[row];
#pragma unroll 8
    for (int h4 = 0; h4 < H / 4; ++h4) {
      float4 w = wr[h4], x = xr4[h4];
      a += w.x * x.x + w.y * x.y + w.z * x.z + w.w * x.w;
    }
    gi[k] = a;
  }
  float hr = gh[(size_t)b * 3 * H + g];
  float hz = gh[(size_t)b * 3 * H + H + g];
  float hnn = gh[(size_t)b * 3 * H + 2 * H + g];
  float r = 1.f / (1.f + expf(-(gi[0] + hr)));
  float z = 1.f / (1.f + expf(-(gi[1] + hz)));
  float n = tanhf(gi[2] + r * hnn);
  float hprev = last_hidden[b * H + g];
  float hnew = (1.f - z) * n + z * hprev;
  out_hidden[b * H + g] = hnew;
  hn[g] = hnew;
  __syncthreads();
  if (g < O) {
    const float4* hn4 = reinterpret_cast<const float4*>(hn);
    const float4* wr = reinterpret_cast<const float4*>(out_W + (size_t)g * H);
    float a = out_b[g];
#pragma unroll 8
    for (int h4 = 0; h4 < H / 4; ++h4) {
      float4 w = wr[h4], x = hn4[h4];
      a += w.x * x.x + w.y * x.y + w.z * x.z + w.w * x.w;
    }
    out_output[b * O + g] = a;
  }
}

extern "C" void kernel_launch(void* const* d_in, const int* in_sizes, int n_in,
                              void* d_out, int out_size, void* d_ws,
                              size_t ws_size, hipStream_t stream) {
  (void)in_sizes; (void)n_in; (void)out_size; (void)ws_size;
  const float* motion      = (const float*)d_in[0];
  const float* last_hidden = (const float*)d_in[1];
  const float* enc         = (const float*)d_in[2];
  const float* attn_W      = (const float*)d_in[3];
  const float* attn_b      = (const float*)d_in[4];
  const float* v           = (const float*)d_in[5];
  const float* pre_W       = (const float*)d_in[6];
  const float* pre_b       = (const float*)d_in[7];
  const float* bn_g        = (const float*)d_in[8];
  const float* bn_b        = (const float*)d_in[9];
  const float* W_ih        = (const float*)d_in[10];
  const float* b_ih        = (const float*)d_in[11];
  const float* W_hh        = (const float*)d_in[12];
  const float* b_hh        = (const float*)d_in[13];
  const float* out_W       = (const float*)d_in[14];
  const float* out_b       = (const float*)d_in[15];

  float* out = (float*)d_out;
  float* out_output = out;
  float* out_hidden = out + B * O;
  float* out_attn   = out + B * O + B * H;

  float* ws = (float*)d_ws;
  float* sc   = ws;                                  // B*T
  float* cp   = sc + (size_t)B * T;                  // NCHUNK*B*H
  float* mbuf = cp + (size_t)NCHUNK * B * H;         // B*NCHUNK
  float* lbuf = mbuf + (size_t)B * NCHUNK;           // B*NCHUNK
  float* hp   = lbuf + (size_t)B * NCHUNK;           // B*H
  float* gh   = hp + (size_t)B * H;                  // 3*B*H
  float* xp   = gh + (size_t)3 * B * H;              // B*H
  _Float16* Bperm = (_Float16*)(xp + (size_t)B * H); // H*H f16

  k0_permW<<<256, 256, 0, stream>>>(attn_W, Bperm);
  k1_hidproj_gh<<<B, 256, 0, stream>>>(last_hidden, attn_W, attn_b, W_hh, b_hh,
                                       hp, gh);
  k2_fused<<<dim3(NCHUNK, B), 256, 0, stream>>>(enc, Bperm, hp, v, sc, cp,
                                                mbuf, lbuf);
  k3_softmax<<<B, 256, 0, stream>>>(sc, out_attn);
  k5_prelinear<<<B, 256, 0, stream>>>(cp, mbuf, lbuf, motion, pre_W, pre_b, xp);
  k6_bn_gru_out<<<B, 256, 0, stream>>>(xp, bn_g, bn_b, gh, W_ih, b_ih,
                                       last_hidden, out_W, out_b, out_output,
                                       out_hidden);
}

// Round 24
// 174.988 us; speedup vs baseline: 1.1093x; 1.0429x over previous
//
#include <hip/hip_runtime.h>
#include <math.h>

#define B 64
#define T 4096
#define H 256
#define D 128
#define O 128
#define EPS 1e-5f

#define NCHUNK 64    // T/64 score chunks (= k2 grid.x)

typedef _Float16 half8 __attribute__((ext_vector_type(8)));
typedef float f32x4 __attribute__((ext_vector_type(4)));

__device__ __forceinline__ float rcp_fast(float x) {
  float r;
  asm("v_rcp_f32 %0, %1" : "=v"(r) : "v"(x));
  return r;
}

// lean tanh: 1 - 2*rcp(exp(2x)+1); exp overflow -> 1, underflow -> -1
__device__ __forceinline__ float tanh_fast(float x) {
  return fmaf(-2.f, rcp_fast(__expf(2.f * x) + 1.f), 1.f);
}

// ---------------- K1: hid_proj + gh, with W_e permute fused as prologue ----
__global__ __launch_bounds__(256) void k1_perm_hidproj_gh(
    const float* __restrict__ last_hidden, const float* __restrict__ attn_W,
    const float* __restrict__ attn_b, const float* __restrict__ W_hh,
    const float* __restrict__ b_hh, float* __restrict__ hid_proj,
    float* __restrict__ gh, _Float16* __restrict__ Bperm) {
  int b = blockIdx.x;
  int g = threadIdx.x;

  // ---- fused k0: each thread permutes 4 Bperm elements (verbatim logic) ----
  {
    int base = (b * 256 + g) * 4;
#pragma unroll
    for (int q = 0; q < 4; ++q) {
      int idx = base + q;
      int j = idx & 7;
      int l = (idx >> 3) & 63;
      int kt = (idx >> 9) & 7;
      int nt = idx >> 12;
      int gg = nt * 16 + (l & 15);
      int k = kt * 32 + ((l >> 4) << 3) + j;
      Bperm[idx] = (_Float16)attn_W[(size_t)gg * (2 * H) + H + k];
    }
  }

  __shared__ __align__(16) float hp[H];
  hp[g] = last_hidden[b * H + g];
  __syncthreads();
  const float4* hp4 = reinterpret_cast<const float4*>(hp);
  const float4* wr = reinterpret_cast<const float4*>(attn_W + (size_t)g * (2 * H));
  float acc = attn_b[g];
#pragma unroll 8
  for (int h4 = 0; h4 < H / 4; ++h4) {
    float4 w = wr[h4], x = hp4[h4];
    acc += w.x * x.x + w.y * x.y + w.z * x.z + w.w * x.w;
  }
  hid_proj[b * H + g] = acc;
#pragma unroll
  for (int k = 0; k < 3; ++k) {
    int row = k * H + g;
    const float4* whr = reinterpret_cast<const float4*>(W_hh + (size_t)row * H);
    float a2 = b_hh[row];
#pragma unroll 8
    for (int h4 = 0; h4 < H / 4; ++h4) {
      float4 w = whr[h4], x = hp4[h4];
      a2 += w.x * x.x + w.y * x.y + w.z * x.z + w.w * x.w;
    }
    gh[(size_t)b * (3 * H) + row] = a2;
  }
}

// ======== K2 fused: scores (MFMA) + chunk-softmax + partial context ========
// R20/R22/R23-verified structure (banked best). TT=64, 256thr, (256,2), LDS
// f16 frags, conflict-free staging; after scores, chunk-local softmax stats
// and partial context accumulated from the SAME LDS fragments (no k4 pass).
__global__ __launch_bounds__(256, 2) void k2_fused(
    const float* __restrict__ enc, const _Float16* __restrict__ Bperm,
    const float* __restrict__ hid_proj, const float* __restrict__ v,
    float* __restrict__ scores, float* __restrict__ cp,
    float* __restrict__ mbuf, float* __restrict__ lbuf) {
  const int b = blockIdx.y;
  const int chunk = blockIdx.x;
  const int t0 = chunk * 64;
  const int tid = threadIdx.x;
  const int wave = tid >> 6;
  const int lane = tid & 63;
  const int r = lane & 15;
  const int grp = lane >> 4;

  __shared__ __align__(16) _Float16 Alds[4 * 8 * 64 * 8];  // 32KB
  __shared__ float spart[4][64];
  __shared__ float wbuf[64];

  // ---- stage enc tile -> f16 fragment order (conflict-free writes) ----
  {
    const int rbase = tid & 7;
    const int kg = tid >> 3;
    const int kt_s = kg >> 2;
    const int lhi = (kg & 3) << 4;
#pragma unroll
    for (int i = 0; i < 8; ++i) {
      int row = i * 8 + rbase;
      const float* src = enc + ((size_t)(t0 + row) * B + b) * H + kg * 8;
      float4 x0 = *reinterpret_cast<const float4*>(src);
      float4 x1 = *reinterpret_cast<const float4*>(src + 4);
      half8 hh;
      hh[0] = (_Float16)x0.x; hh[1] = (_Float16)x0.y;
      hh[2] = (_Float16)x0.z; hh[3] = (_Float16)x0.w;
      hh[4] = (_Float16)x1.x; hh[5] = (_Float16)x1.y;
      hh[6] = (_Float16)x1.z; hh[7] = (_Float16)x1.w;
      int m = row >> 4;
      int lane_s = lhi | (row & 15);
      *reinterpret_cast<half8*>(&Alds[(((m * 8) + kt_s) * 64 + lane_s) * 8]) = hh;
    }
  }
  __syncthreads();

  const half8* bp = reinterpret_cast<const half8*>(Bperm);
  const int ntb = wave * 4;

  f32x4 acc[4][4];
#pragma unroll
  for (int m = 0; m < 4; ++m)
#pragma unroll
    for (int n = 0; n < 4; ++n) acc[m][n] = (f32x4){0.f, 0.f, 0.f, 0.f};

  half8 bB[2][4];
#pragma unroll
  for (int n = 0; n < 4; ++n) bB[0][n] = bp[((ntb + n) * 8 + 0) * 64 + lane];

#pragma unroll
  for (int kt = 0; kt < 8; ++kt) {
    if (kt < 7) {
#pragma unroll
      for (int n = 0; n < 4; ++n)
        bB[(kt + 1) & 1][n] = bp[((ntb + n) * 8 + kt + 1) * 64 + lane];
    }
    half8 a[4];
#pragma unroll
    for (int m = 0; m < 4; ++m)
      a[m] = *reinterpret_cast<const half8*>(&Alds[((m * 8 + kt) * 64 + lane) * 8]);
#pragma unroll
    for (int m = 0; m < 4; ++m)
#pragma unroll
      for (int n = 0; n < 4; ++n)
        acc[m][n] = __builtin_amdgcn_mfma_f32_16x16x32_f16(
            a[m], bB[kt & 1][n], acc[m][n], 0, 0, 0);
  }

  // ---- score epilogue (lean tanh) ----
  float hpv[4], vg[4];
#pragma unroll
  for (int n = 0; n < 4; ++n) {
    int g = (ntb + n) * 16 + r;
    hpv[n] = hid_proj[b * H + g];
    vg[n] = v[g];
  }
#pragma unroll
  for (int m = 0; m < 4; ++m) {
#pragma unroll
    for (int i = 0; i < 4; ++i) {
      float s = 0.f;
#pragma unroll
      for (int n = 0; n < 4; ++n)
        s = fmaf(vg[n], tanh_fast(acc[m][n][i] + hpv[n]), s);
      s += __shfl_xor(s, 1);
      s += __shfl_xor(s, 2);
      s += __shfl_xor(s, 4);
      s += __shfl_xor(s, 8);
      if (r == 0) spart[wave][m * 16 + grp * 4 + i] = s;
    }
  }
  __syncthreads();

  // ---- wave 0: finalize scores, chunk-local softmax stats ----
  if (tid < 64) {
    float sv = spart[0][tid] + spart[1][tid] + spart[2][tid] + spart[3][tid];
    scores[(size_t)b * T + t0 + tid] = sv;
    float mc = sv;
#pragma unroll
    for (int off = 32; off > 0; off >>= 1) mc = fmaxf(mc, __shfl_xor(mc, off));
    float w = __expf(sv - mc);
    wbuf[tid] = w;
    float lc = w;
#pragma unroll
    for (int off = 32; off > 0; off >>= 1) lc += __shfl_xor(lc, off);
    if (tid == 0) {
      mbuf[b * NCHUNK + chunk] = mc;
      lbuf[b * NCHUNK + chunk] = lc;
    }
  }
  __syncthreads();

  // ---- partial context: wave handles kt = 2*wave, 2*wave+1 ----
#pragma unroll
  for (int kk = 0; kk < 2; ++kk) {
    const int kt = wave * 2 + kk;
    float cacc[8];
#pragma unroll
    for (int j = 0; j < 8; ++j) cacc[j] = 0.f;
#pragma unroll
    for (int m = 0; m < 4; ++m) {
      half8 a = *reinterpret_cast<const half8*>(
          &Alds[((m * 8 + kt) * 64 + lane) * 8]);
      float wt = wbuf[m * 16 + r];
#pragma unroll
      for (int j = 0; j < 8; ++j) cacc[j] = fmaf(wt, (float)a[j], cacc[j]);
    }
    // reduce over r (16 lanes per grp-group)
#pragma unroll
    for (int j = 0; j < 8; ++j) {
      float s = cacc[j];
      s += __shfl_xor(s, 1);
      s += __shfl_xor(s, 2);
      s += __shfl_xor(s, 4);
      s += __shfl_xor(s, 8);
      cacc[j] = s;
    }
    if (r == 0) {
      float4 lo = {cacc[0], cacc[1], cacc[2], cacc[3]};
      float4 hi = {cacc[4], cacc[5], cacc[6], cacc[7]};
      float* dst = cp + ((size_t)chunk * B + b) * H + kt * 32 + grp * 8;
      *reinterpret_cast<float4*>(dst) = lo;
      *reinterpret_cast<float4*>(dst + 4) = hi;
    }
  }
}

// ==== K35: block-role merge of k3 (softmax, blocks 0..63) and k5 (prelinear,
// blocks 64..127). Bodies verbatim; branch is block-uniform. ====
__global__ __launch_bounds__(256) void k35_softmax_prelinear(
    const float* __restrict__ scores, float* __restrict__ attn_out,
    const float* __restrict__ cp, const float* __restrict__ mbuf,
    const float* __restrict__ lbuf, const float* __restrict__ motion,
    const float* __restrict__ pre_W, const float* __restrict__ pre_b,
    float* __restrict__ xpre) {
  __shared__ float redm[4];
  __shared__ float reds[4];
  __shared__ float mc[NCHUNK], lc[NCHUNK];
  __shared__ __align__(16) float cm[D + H];

  int tid = threadIdx.x;
  if (blockIdx.x < B) {
    // ---------------- k3 body ----------------
    int b = blockIdx.x;
    float vals[16];
    const float4* sp = reinterpret_cast<const float4*>(scores + (size_t)b * T);
#pragma unroll
    for (int i = 0; i < 4; ++i) {
      float4 x = sp[i * 256 + tid];
      vals[i * 4 + 0] = x.x; vals[i * 4 + 1] = x.y;
      vals[i * 4 + 2] = x.z; vals[i * 4 + 3] = x.w;
    }
    float m = -INFINITY;
#pragma unroll
    for (int i = 0; i < 16; ++i) m = fmaxf(m, vals[i]);
    for (int off = 32; off > 0; off >>= 1) m = fmaxf(m, __shfl_xor(m, off));
    int wave = tid >> 6, lane = tid & 63;
    if (lane == 0) redm[wave] = m;
    __syncthreads();
    m = fmaxf(fmaxf(redm[0], redm[1]), fmaxf(redm[2], redm[3]));
    float s = 0.f;
#pragma unroll
    for (int i = 0; i < 16; ++i) {
      vals[i] = expf(vals[i] - m);
      s += vals[i];
    }
    for (int off = 32; off > 0; off >>= 1) s += __shfl_xor(s, off);
    if (lane == 0) reds[wave] = s;
    __syncthreads();
    s = reds[0] + reds[1] + reds[2] + reds[3];
    float inv = 1.f / s;
    float4* op = reinterpret_cast<float4*>(attn_out + (size_t)b * T);
#pragma unroll
    for (int i = 0; i < 4; ++i) {
      float4 x;
      x.x = vals[i * 4 + 0] * inv; x.y = vals[i * 4 + 1] * inv;
      x.z = vals[i * 4 + 2] * inv; x.w = vals[i * 4 + 3] * inv;
      op[i * 256 + tid] = x;
    }
  } else {
    // ---------------- k5 body ----------------
    int b = blockIdx.x - B;
    int g = tid;
    if (g < NCHUNK) {
      mc[g] = mbuf[b * NCHUNK + g];
      lc[g] = lbuf[b * NCHUNK + g];
    }
    __syncthreads();
    float m = -INFINITY;
#pragma unroll 8
    for (int c = 0; c < NCHUNK; ++c) m = fmaxf(m, mc[c]);
    float l = 0.f, ctx = 0.f;
#pragma unroll 4
    for (int c = 0; c < NCHUNK; ++c) {
      float al = __expf(mc[c] - m);
      l += lc[c] * al;
      ctx += al * cp[((size_t)c * B + b) * H + g];
    }
    cm[D + g] = ctx / l;
    if (g < D) cm[g] = motion[b * D + g];
    __syncthreads();
    const float4* cm4 = reinterpret_cast<const float4*>(cm);
    const float4* wr = reinterpret_cast<const float4*>(pre_W + (size_t)g * (D + H));
    float acc = pre_b[g];
#pragma unroll 8
    for (int j = 0; j < (D + H) / 4; ++j) {
      float4 w = wr[j], x = cm4[j];
      acc += w.x * x.x + w.y * x.y + w.z * x.z + w.w * x.w;
    }
    xpre[b * H + g] = acc;
  }
}

// ---------------- K6: batchnorm + relu + GRU cell + output projection ----
// (R23-verified: k5b fused in; BN stats computed redundantly per block.)
__global__ __launch_bounds__(256) void k6_bn_gru_out(
    const float* __restrict__ xpre, const float* __restrict__ gamma,
    const float* __restrict__ beta, const float* __restrict__ gh,
    const float* __restrict__ W_ih, const float* __restrict__ b_ih,
    const float* __restrict__ last_hidden, const float* __restrict__ out_W,
    const float* __restrict__ out_b, float* __restrict__ out_output,
    float* __restrict__ out_hidden) {
  int b = blockIdx.x;
  int g = threadIdx.x;
  __shared__ __align__(16) float xr[H];
  __shared__ __align__(16) float hn[H];

  // ---- BN stats over batch for feature g (same order as k5b) ----
  float mu = 0.f;
  for (int bb = 0; bb < B; ++bb) mu += xpre[bb * H + g];
  mu *= (1.f / B);
  float var = 0.f;
  for (int bb = 0; bb < B; ++bb) {
    float d = xpre[bb * H + g] - mu;
    var += d * d;
  }
  var *= (1.f / B);
  float sc = gamma[g] * rsqrtf(var + EPS);
  float bi = beta[g];
  float y = (xpre[b * H + g] - mu) * sc + bi;
  xr[g] = fmaxf(y, 0.f);
  __syncthreads();

  const float4* xr4 = reinterpret_cast<const float4*>(xr);
  float gi[3];
#pragma unroll
  for (int k = 0; k < 3; ++k) {
    int row = k * H + g;
    const float4* wr = reinterpret_cast<const float4*>(W_ih + (size_t)row * H);
    float a = b_ih[row];
#pragma unroll 8
    for (int h4 = 0; h4 < H / 4; ++h4) {
      float4 w = wr[h4], x = xr4[h4];
      a += w.x * x.x + w.y * x.y + w.z * x.z + w.w * x.w;
    }
    gi[k] = a;
  }
  float hr = gh[(size_t)b * 3 * H + g];
  float hz = gh[(size_t)b * 3 * H + H + g];
  float hnn = gh[(size_t)b * 3 * H + 2 * H + g];
  float r = 1.f / (1.f + expf(-(gi[0] + hr)));
  float z = 1.f / (1.f + expf(-(gi[1] + hz)));
  float n = tanhf(gi[2] + r * hnn);
  float hprev = last_hidden[b * H + g];
  float hnew = (1.f - z) * n + z * hprev;
  out_hidden[b * H + g] = hnew;
  hn[g] = hnew;
  __syncthreads();
  if (g < O) {
    const float4* hn4 = reinterpret_cast<const float4*>(hn);
    const float4* wr = reinterpret_cast<const float4*>(out_W + (size_t)g * H);
    float a = out_b[g];
#pragma unroll 8
    for (int h4 = 0; h4 < H / 4; ++h4) {
      float4 w = wr[h4], x = hn4[h4];
      a += w.x * x.x + w.y * x.y + w.z * x.z + w.w * x.w;
    }
    out_output[b * O + g] = a;
  }
}

extern "C" void kernel_launch(void* const* d_in, const int* in_sizes, int n_in,
                              void* d_out, int out_size, void* d_ws,
                              size_t ws_size, hipStream_t stream) {
  (void)in_sizes; (void)n_in; (void)out_size; (void)ws_size;
  const float* motion      = (const float*)d_in[0];
  const float* last_hidden = (const float*)d_in[1];
  const float* enc         = (const float*)d_in[2];
  const float* attn_W      = (const float*)d_in[3];
  const float* attn_b      = (const float*)d_in[4];
  const float* v           = (const float*)d_in[5];
  const float* pre_W       = (const float*)d_in[6];
  const float* pre_b       = (const float*)d_in[7];
  const float* bn_g        = (const float*)d_in[8];
  const float* bn_b        = (const float*)d_in[9];
  const float* W_ih        = (const float*)d_in[10];
  const float* b_ih        = (const float*)d_in[11];
  const float* W_hh        = (const float*)d_in[12];
  const float* b_hh        = (const float*)d_in[13];
  const float* out_W       = (const float*)d_in[14];
  const float* out_b       = (const float*)d_in[15];

  float* out = (float*)d_out;
  float* out_output = out;
  float* out_hidden = out + B * O;
  float* out_attn   = out + B * O + B * H;

  float* ws = (float*)d_ws;
  float* sc   = ws;                                  // B*T
  float* cp   = sc + (size_t)B * T;                  // NCHUNK*B*H
  float* mbuf = cp + (size_t)NCHUNK * B * H;         // B*NCHUNK
  float* lbuf = mbuf + (size_t)B * NCHUNK;           // B*NCHUNK
  float* hp   = lbuf + (size_t)B * NCHUNK;           // B*H
  float* gh   = hp + (size_t)B * H;                  // 3*B*H
  float* xp   = gh + (size_t)3 * B * H;              // B*H
  _Float16* Bperm = (_Float16*)(xp + (size_t)B * H); // H*H f16

  k1_perm_hidproj_gh<<<B, 256, 0, stream>>>(last_hidden, attn_W, attn_b, W_hh,
                                            b_hh, hp, gh, Bperm);
  k2_fused<<<dim3(NCHUNK, B), 256, 0, stream>>>(enc, Bperm, hp, v, sc, cp,
                                                mbuf, lbuf);
  k35_softmax_prelinear<<<2 * B, 256, 0, stream>>>(sc, out_attn, cp, mbuf,
                                                   lbuf, motion, pre_W, pre_b,
                                                   xp);
  k6_bn_gru_out<<<B, 256, 0, stream>>>(xp, bn_g, bn_b, gh, W_ih, b_ih,
                                       last_hidden, out_W, out_b, out_output,
                                       out_hidden);
}

// Round 25
// 174.842 us; speedup vs baseline: 1.1102x; 1.0008x over previous
//
#include <hip/hip_runtime.h>
#include <math.h>

#define B 64
#define T 4096
#define H 256
#define D 128
#define O 128
#define EPS 1e-5f

#define NCHUNK 64    // T/64 score chunks (= k2 grid.x)

typedef _Float16 half8 __attribute__((ext_vector_type(8)));
typedef float f32x4 __attribute__((ext_vector_type(4)));

__device__ __forceinline__ float rcp_fast(float x) {
  float r;
  asm("v_rcp_f32 %0, %1" : "=v"(r) : "v"(x));
  return r;
}

// lean tanh: 1 - 2*rcp(exp(2x)+1); exp overflow -> 1, underflow -> -1
__device__ __forceinline__ float tanh_fast(float x) {
  return fmaf(-2.f, rcp_fast(__expf(2.f * x) + 1.f), 1.f);
}

// ---------------- K1: hid_proj + gh, with W_e permute fused as prologue ----
__global__ __launch_bounds__(256) void k1_perm_hidproj_gh(
    const float* __restrict__ last_hidden, const float* __restrict__ attn_W,
    const float* __restrict__ attn_b, const float* __restrict__ W_hh,
    const float* __restrict__ b_hh, float* __restrict__ hid_proj,
    float* __restrict__ gh, _Float16* __restrict__ Bperm) {
  int b = blockIdx.x;
  int g = threadIdx.x;

  // ---- fused k0: each thread permutes 4 Bperm elements (verbatim logic) ----
  {
    int base = (b * 256 + g) * 4;
#pragma unroll
    for (int q = 0; q < 4; ++q) {
      int idx = base + q;
      int j = idx & 7;
      int l = (idx >> 3) & 63;
      int kt = (idx >> 9) & 7;
      int nt = idx >> 12;
      int gg = nt * 16 + (l & 15);
      int k = kt * 32 + ((l >> 4) << 3) + j;
      Bperm[idx] = (_Float16)attn_W[(size_t)gg * (2 * H) + H + k];
    }
  }

  __shared__ __align__(16) float hp[H];
  hp[g] = last_hidden[b * H + g];
  __syncthreads();
  const float4* hp4 = reinterpret_cast<const float4*>(hp);
  const float4* wr = reinterpret_cast<const float4*>(attn_W + (size_t)g * (2 * H));
  float acc = attn_b[g];
#pragma unroll 8
  for (int h4 = 0; h4 < H / 4; ++h4) {
    float4 w = wr[h4], x = hp4[h4];
    acc += w.x * x.x + w.y * x.y + w.z * x.z + w.w * x.w;
  }
  hid_proj[b * H + g] = acc;
#pragma unroll
  for (int k = 0; k < 3; ++k) {
    int row = k * H + g;
    const float4* whr = reinterpret_cast<const float4*>(W_hh + (size_t)row * H);
    float a2 = b_hh[row];
#pragma unroll 8
    for (int h4 = 0; h4 < H / 4; ++h4) {
      float4 w = whr[h4], x = hp4[h4];
      a2 += w.x * x.x + w.y * x.y + w.z * x.z + w.w * x.w;
    }
    gh[(size_t)b * (3 * H) + row] = a2;
  }
}

// ======== K2 fused: scores (MFMA) + chunk-softmax + partial context ========
// Banked-best structure (R20/R22/R23/R24). TT=64, 256thr, (256,2), LDS
// f16 frags, conflict-free staging; after scores, chunk-local softmax stats
// and partial context accumulated from the SAME LDS fragments (no k4 pass).
__global__ __launch_bounds__(256, 2) void k2_fused(
    const float* __restrict__ enc, const _Float16* __restrict__ Bperm,
    const float* __restrict__ hid_proj, const float* __restrict__ v,
    float* __restrict__ scores, float* __restrict__ cp,
    float* __restrict__ mbuf, float* __restrict__ lbuf) {
  const int b = blockIdx.y;
  const int chunk = blockIdx.x;
  const int t0 = chunk * 64;
  const int tid = threadIdx.x;
  const int wave = tid >> 6;
  const int lane = tid & 63;
  const int r = lane & 15;
  const int grp = lane >> 4;

  __shared__ __align__(16) _Float16 Alds[4 * 8 * 64 * 8];  // 32KB
  __shared__ float spart[4][64];
  __shared__ float wbuf[64];

  // ---- stage enc tile -> f16 fragment order (conflict-free writes) ----
  {
    const int rbase = tid & 7;
    const int kg = tid >> 3;
    const int kt_s = kg >> 2;
    const int lhi = (kg & 3) << 4;
#pragma unroll
    for (int i = 0; i < 8; ++i) {
      int row = i * 8 + rbase;
      const float* src = enc + ((size_t)(t0 + row) * B + b) * H + kg * 8;
      float4 x0 = *reinterpret_cast<const float4*>(src);
      float4 x1 = *reinterpret_cast<const float4*>(src + 4);
      half8 hh;
      hh[0] = (_Float16)x0.x; hh[1] = (_Float16)x0.y;
      hh[2] = (_Float16)x0.z; hh[3] = (_Float16)x0.w;
      hh[4] = (_Float16)x1.x; hh[5] = (_Float16)x1.y;
      hh[6] = (_Float16)x1.z; hh[7] = (_Float16)x1.w;
      int m = row >> 4;
      int lane_s = lhi | (row & 15);
      *reinterpret_cast<half8*>(&Alds[(((m * 8) + kt_s) * 64 + lane_s) * 8]) = hh;
    }
  }
  __syncthreads();

  const half8* bp = reinterpret_cast<const half8*>(Bperm);
  const int ntb = wave * 4;

  f32x4 acc[4][4];
#pragma unroll
  for (int m = 0; m < 4; ++m)
#pragma unroll
    for (int n = 0; n < 4; ++n) acc[m][n] = (f32x4){0.f, 0.f, 0.f, 0.f};

  half8 bB[2][4];
#pragma unroll
  for (int n = 0; n < 4; ++n) bB[0][n] = bp[((ntb + n) * 8 + 0) * 64 + lane];

#pragma unroll
  for (int kt = 0; kt < 8; ++kt) {
    if (kt < 7) {
#pragma unroll
      for (int n = 0; n < 4; ++n)
        bB[(kt + 1) & 1][n] = bp[((ntb + n) * 8 + kt + 1) * 64 + lane];
    }
    half8 a[4];
#pragma unroll
    for (int m = 0; m < 4; ++m)
      a[m] = *reinterpret_cast<const half8*>(&Alds[((m * 8 + kt) * 64 + lane) * 8]);
#pragma unroll
    for (int m = 0; m < 4; ++m)
#pragma unroll
      for (int n = 0; n < 4; ++n)
        acc[m][n] = __builtin_amdgcn_mfma_f32_16x16x32_f16(
            a[m], bB[kt & 1][n], acc[m][n], 0, 0, 0);
  }

  // ---- score epilogue (lean tanh) ----
  float hpv[4], vg[4];
#pragma unroll
  for (int n = 0; n < 4; ++n) {
    int g = (ntb + n) * 16 + r;
    hpv[n] = hid_proj[b * H + g];
    vg[n] = v[g];
  }
#pragma unroll
  for (int m = 0; m < 4; ++m) {
#pragma unroll
    for (int i = 0; i < 4; ++i) {
      float s = 0.f;
#pragma unroll
      for (int n = 0; n < 4; ++n)
        s = fmaf(vg[n], tanh_fast(acc[m][n][i] + hpv[n]), s);
      s += __shfl_xor(s, 1);
      s += __shfl_xor(s, 2);
      s += __shfl_xor(s, 4);
      s += __shfl_xor(s, 8);
      if (r == 0) spart[wave][m * 16 + grp * 4 + i] = s;
    }
  }
  __syncthreads();

  // ---- wave 0: finalize scores, chunk-local softmax stats ----
  if (tid < 64) {
    float sv = spart[0][tid] + spart[1][tid] + spart[2][tid] + spart[3][tid];
    scores[(size_t)b * T + t0 + tid] = sv;
    float mc = sv;
#pragma unroll
    for (int off = 32; off > 0; off >>= 1) mc = fmaxf(mc, __shfl_xor(mc, off));
    float w = __expf(sv - mc);
    wbuf[tid] = w;
    float lc = w;
#pragma unroll
    for (int off = 32; off > 0; off >>= 1) lc += __shfl_xor(lc, off);
    if (tid == 0) {
      mbuf[b * NCHUNK + chunk] = mc;
      lbuf[b * NCHUNK + chunk] = lc;
    }
  }
  __syncthreads();

  // ---- partial context: wave handles kt = 2*wave, 2*wave+1 ----
#pragma unroll
  for (int kk = 0; kk < 2; ++kk) {
    const int kt = wave * 2 + kk;
    float cacc[8];
#pragma unroll
    for (int j = 0; j < 8; ++j) cacc[j] = 0.f;
#pragma unroll
    for (int m = 0; m < 4; ++m) {
      half8 a = *reinterpret_cast<const half8*>(
          &Alds[((m * 8 + kt) * 64 + lane) * 8]);
      float wt = wbuf[m * 16 + r];
#pragma unroll
      for (int j = 0; j < 8; ++j) cacc[j] = fmaf(wt, (float)a[j], cacc[j]);
    }
    // reduce over r (16 lanes per grp-group)
#pragma unroll
    for (int j = 0; j < 8; ++j) {
      float s = cacc[j];
      s += __shfl_xor(s, 1);
      s += __shfl_xor(s, 2);
      s += __shfl_xor(s, 4);
      s += __shfl_xor(s, 8);
      cacc[j] = s;
    }
    if (r == 0) {
      float4 lo = {cacc[0], cacc[1], cacc[2], cacc[3]};
      float4 hi = {cacc[4], cacc[5], cacc[6], cacc[7]};
      float* dst = cp + ((size_t)chunk * B + b) * H + kt * 32 + grp * 8;
      *reinterpret_cast<float4*>(dst) = lo;
      *reinterpret_cast<float4*>(dst + 4) = hi;
    }
  }
}

// ==== K35: block-role merge of k3 (softmax, blocks 0..63) and k5 (prelinear,
// blocks 64..127). Bodies verbatim; branch is block-uniform. ====
__global__ __launch_bounds__(256) void k35_softmax_prelinear(
    const float* __restrict__ scores, float* __restrict__ attn_out,
    const float* __restrict__ cp, const float* __restrict__ mbuf,
    const float* __restrict__ lbuf, const float* __restrict__ motion,
    const float* __restrict__ pre_W, const float* __restrict__ pre_b,
    float* __restrict__ xpre) {
  __shared__ float redm[4];
  __shared__ float reds[4];
  __shared__ float mc[NCHUNK], lc[NCHUNK];
  __shared__ __align__(16) float cm[D + H];

  int tid = threadIdx.x;
  if (blockIdx.x < B) {
    // ---------------- k3 body ----------------
    int b = blockIdx.x;
    float vals[16];
    const float4* sp = reinterpret_cast<const float4*>(scores + (size_t)b * T);
#pragma unroll
    for (int i = 0; i < 4; ++i) {
      float4 x = sp[i * 256 + tid];
      vals[i * 4 + 0] = x.x; vals[i * 4 + 1] = x.y;
      vals[i * 4 + 2] = x.z; vals[i * 4 + 3] = x.w;
    }
    float m = -INFINITY;
#pragma unroll
    for (int i = 0; i < 16; ++i) m = fmaxf(m, vals[i]);
    for (int off = 32; off > 0; off >>= 1) m = fmaxf(m, __shfl_xor(m, off));
    int wave = tid >> 6, lane = tid & 63;
    if (lane == 0) redm[wave] = m;
    __syncthreads();
    m = fmaxf(fmaxf(redm[0], redm[1]), fmaxf(redm[2], redm[3]));
    float s = 0.f;
#pragma unroll
    for (int i = 0; i < 16; ++i) {
      vals[i] = expf(vals[i] - m);
      s += vals[i];
    }
    for (int off = 32; off > 0; off >>= 1) s += __shfl_xor(s, off);
    if (lane == 0) reds[wave] = s;
    __syncthreads();
    s = reds[0] + reds[1] + reds[2] + reds[3];
    float inv = 1.f / s;
    float4* op = reinterpret_cast<float4*>(attn_out + (size_t)b * T);
#pragma unroll
    for (int i = 0; i < 4; ++i) {
      float4 x;
      x.x = vals[i * 4 + 0] * inv; x.y = vals[i * 4 + 1] * inv;
      x.z = vals[i * 4 + 2] * inv; x.w = vals[i * 4 + 3] * inv;
      op[i * 256 + tid] = x;
    }
  } else {
    // ---------------- k5 body ----------------
    int b = blockIdx.x - B;
    int g = tid;
    if (g < NCHUNK) {
      mc[g] = mbuf[b * NCHUNK + g];
      lc[g] = lbuf[b * NCHUNK + g];
    }
    __syncthreads();
    float m = -INFINITY;
#pragma unroll 8
    for (int c = 0; c < NCHUNK; ++c) m = fmaxf(m, mc[c]);
    float l = 0.f, ctx = 0.f;
#pragma unroll 4
    for (int c = 0; c < NCHUNK; ++c) {
      float al = __expf(mc[c] - m);
      l += lc[c] * al;
      ctx += al * cp[((size_t)c * B + b) * H + g];
    }
    cm[D + g] = ctx / l;
    if (g < D) cm[g] = motion[b * D + g];
    __syncthreads();
    const float4* cm4 = reinterpret_cast<const float4*>(cm);
    const float4* wr = reinterpret_cast<const float4*>(pre_W + (size_t)g * (D + H));
    float acc = pre_b[g];
#pragma unroll 8
    for (int j = 0; j < (D + H) / 4; ++j) {
      float4 w = wr[j], x = cm4[j];
      acc += w.x * x.x + w.y * x.y + w.z * x.z + w.w * x.w;
    }
    xpre[b * H + g] = acc;
  }
}

// ---------------- K6: batchnorm + relu + GRU cell + output projection ----
// (R23-verified: k5b fused in; BN stats computed redundantly per block.)
__global__ __launch_bounds__(256) void k6_bn_gru_out(
    const float* __restrict__ xpre, const float* __restrict__ gamma,
    const float* __restrict__ beta, const float* __restrict__ gh,
    const float* __restrict__ W_ih, const float* __restrict__ b_ih,
    const float* __restrict__ last_hidden, const float* __restrict__ out_W,
    const float* __restrict__ out_b, float* __restrict__ out_output,
    float* __restrict__ out_hidden) {
  int b = blockIdx.x;
  int g = threadIdx.x;
  __shared__ __align__(16) float xr[H];
  __shared__ __align__(16) float hn[H];

  // ---- BN stats over batch for feature g (same order as k5b) ----
  float mu = 0.f;
  for (int bb = 0; bb < B; ++bb) mu += xpre[bb * H + g];
  mu *= (1.f / B);
  float var = 0.f;
  for (int bb = 0; bb < B; ++bb) {
    float d = xpre[bb * H + g] - mu;
    var += d * d;
  }
  var *= (1.f / B);
  float sc = gamma[g] * rsqrtf(var + EPS);
  float bi = beta[g];
  float y = (xpre[b * H + g] - mu) * sc + bi;
  xr[g] = fmaxf(y, 0.f);
  __syncthreads();

  const float4* xr4 = reinterpret_cast<const float4*>(xr);
  float gi[3];
#pragma unroll
  for (int k = 0; k < 3; ++k) {
    int row = k * H + g;
    const float4* wr = reinterpret_cast<const float4*>(W_ih + (size_t)row * H);
    float a = b_ih[row];
#pragma unroll 8
    for (int h4 = 0; h4 < H / 4; ++h4) {
      float4 w = wr[h4], x = xr4[h4];
      a += w.x * x.x + w.y * x.y + w.z * x.z + w.w * x.w;
    }
    gi[k] = a;
  }
  float hr = gh[(size_t)b * 3 * H + g];
  float hz = gh[(size_t)b * 3 * H + H + g];
  float hnn = gh[(size_t)b * 3 * H + 2 * H + g];
  float r = 1.f / (1.f + expf(-(gi[0] + hr)));
  float z = 1.f / (1.f + expf(-(gi[1] + hz)));
  float n = tanhf(gi[2] + r * hnn);
  float hprev = last_hidden[b * H + g];
  float hnew = (1.f - z) * n + z * hprev;
  out_hidden[b * H + g] = hnew;
  hn[g] = hnew;
  __syncthreads();
  if (g < O) {
    const float4* hn4 = reinterpret_cast<const float4*>(hn);
    const float4* wr = reinterpret_cast<const float4*>(out_W + (size_t)g * H);
    float a = out_b[g];
#pragma unroll 8
    for (int h4 = 0; h4 < H / 4; ++h4) {
      float4 w = wr[h4], x = hn4[h4];
      a += w.x * x.x + w.y * x.y + w.z * x.z + w.w * x.w;
    }
    out_output[b * O + g] = a;
  }
}

extern "C" void kernel_launch(void* const* d_in, const int* in_sizes, int n_in,
                              void* d_out, int out_size, void* d_ws,
                              size_t ws_size, hipStream_t stream) {
  (void)in_sizes; (void)n_in; (void)out_size; (void)ws_size;
  const float* motion      = (const float*)d_in[0];
  const float* last_hidden = (const float*)d_in[1];
  const float* enc         = (const float*)d_in[2];
  const float* attn_W      = (const float*)d_in[3];
  const float* attn_b      = (const float*)d_in[4];
  const float* v           = (const float*)d_in[5];
  const float* pre_W       = (const float*)d_in[6];
  const float* pre_b       = (const float*)d_in[7];
  const float* bn_g        = (const float*)d_in[8];
  const float* bn_b        = (const float*)d_in[9];
  const float* W_ih        = (const float*)d_in[10];
  const float* b_ih        = (const float*)d_in[11];
  const float* W_hh        = (const float*)d_in[12];
  const float* b_hh        = (const float*)d_in[13];
  const float* out_W       = (const float*)d_in[14];
  const float* out_b       = (const float*)d_in[15];

  float* out = (float*)d_out;
  float* out_output = out;
  float* out_hidden = out + B * O;
  float* out_attn   = out + B * O + B * H;

  float* ws = (float*)d_ws;
  float* sc   = ws;                                  // B*T
  float* cp   = sc + (size_t)B * T;                  // NCHUNK*B*H
  float* mbuf = cp + (size_t)NCHUNK * B * H;         // B*NCHUNK
  float* lbuf = mbuf + (size_t)B * NCHUNK;           // B*NCHUNK
  float* hp   = lbuf + (size_t)B * NCHUNK;           // B*H
  float* gh   = hp + (size_t)B * H;                  // 3*B*H
  float* xp   = gh + (size_t)3 * B * H;              // B*H
  _Float16* Bperm = (_Float16*)(xp + (size_t)B * H); // H*H f16

  k1_perm_hidproj_gh<<<B, 256, 0, stream>>>(last_hidden, attn_W, attn_b, W_hh,
                                            b_hh, hp, gh, Bperm);
  k2_fused<<<dim3(NCHUNK, B), 256, 0, stream>>>(enc, Bperm, hp, v, sc, cp,
                                                mbuf, lbuf);
  k35_softmax_prelinear<<<2 * B, 256, 0, stream>>>(sc, out_attn, cp, mbuf,
                                                   lbuf, motion, pre_W, pre_b,
                                                   xp);
  k6_bn_gru_out<<<B, 256, 0, stream>>>(xp, bn_g, bn_b, gh, W_ih, b_ih,
                                       last_hidden, out_W, out_b, out_output,
                                       out_hidden);
}